// Round 4
// baseline (341.344 us; speedup 1.0000x reference)
//
#include <hip/hip_runtime.h>

#define EPS 1e-6f
#define MAX_C 1000     // problem-fixed class count
#define W 32           // columns per slice-block (acc = 1000*32*4 = 125 KB LDS)
#define TR 256         // rows per staged tile (stage = 32 KB)
#define RPC 4096       // rows per chunk
#define SBLK 1024      // 16 waves

// ws layout (4-byte elems):
//   [0]      int   counts[C]
//   [C]      float loss_acc
//   [C+1]    float npres_acc
//   [C+2]    int   done
//   [C+3]    float partials[NCHUNKS * C * D]   (32 MB; fully overwritten)
// memset zeroes the first C+3 elems only.

// Streaming scatter segment-sum, zero in-loop atomics, latency-overlapped.
// Block (slice, chunk) streams 256-row tiles of its 32-col slice into LDS.
// Wave w exclusively owns classes with (label & 15) == w. Matched rows are
// processed in batches of 8 (half-wave 0: rows 0-3, half 1: rows 4-7; lane =
// column) with register dedup of equal labels, so the 4 stage reads + 4 acc
// reads per half are independent and their LDS latencies overlap.
__global__ __launch_bounds__(SBLK)
void stream_kernel(const float* __restrict__ feats,
                   const int* __restrict__ lbls,
                   float* __restrict__ partials,
                   int* __restrict__ counts,
                   int n, int d, int nslices, int c_total) {
    int slice = blockIdx.x % nslices;
    int chunk = blockIdx.x / nslices;
    int t    = threadIdx.x;
    int w    = t >> 6;          // wave 0..15 = class-group owner
    int lane = t & 63;
    int half = lane >> 5;
    int col  = lane & 31;

    __shared__ float acc[MAX_C * W];                 // 125 KB
    __shared__ __align__(16) float stage[TR * W];    // 32 KB (histo scratch first)
    __shared__ int lbl_t[TR];                        // 1 KB

    int cW = c_total * W;
    int base = chunk * RPC;
    int rows = RPC; if (base + rows > n) rows = n - base;
    int ntiles = (rows + TR - 1) / TR;

    const float* fbase = feats + (size_t)base * d + slice * W;
    int sr0 = t >> 3;            // rows 0..127 of tile
    int sr1 = sr0 + 128;         // rows 128..255
    int sc4 = t & 7;             // float4 column within slice

    // ---- prologue: issue tile 0 loads (in flight during init/histo) ----
    float4 p0 = make_float4(0.f, 0.f, 0.f, 0.f), p1 = p0;
    int plab = -1;
    if (sr0 < rows) p0 = *(const float4*)(fbase + (size_t)sr0 * d + sc4 * 4);
    if (sr1 < rows) p1 = *(const float4*)(fbase + (size_t)sr1 * d + sc4 * 4);
    if (t < TR) plab = (t < rows) ? lbls[base + t] : -1;

    for (int i = t; i < cW; i += SBLK) acc[i] = 0.0f;

    // slice-0 blocks also produce the per-class counts (reuse stage as scratch)
    if (slice == 0) {
        int* hist = (int*)stage;
        for (int i = t; i < c_total; i += SBLK) hist[i] = 0;
        __syncthreads();
        for (int i = t; i < rows; i += SBLK) atomicAdd(&hist[lbls[base + i]], 1);
        __syncthreads();
        for (int i = t; i < c_total; i += SBLK) {
            int h = hist[i];
            if (h) atomicAdd(&counts[i], h);
        }
    }
    __syncthreads();            // acc zeroed, histo scratch done

    if (t < TR) lbl_t[t] = plab;
    *(float4*)&stage[sr0 * W + sc4 * 4] = p0;
    *(float4*)&stage[sr1 * W + sc4 * 4] = p1;
    __syncthreads();            // tile 0 staged

    for (int tile = 0; tile < ntiles; ++tile) {
        // T14: issue next tile's global loads before processing current tile
        if (tile + 1 < ntiles) {
            int nb = (tile + 1) * TR;
            p0 = make_float4(0.f, 0.f, 0.f, 0.f); p1 = p0; plab = -1;
            int r0g = nb + sr0, r1g = nb + sr1;
            if (r0g < rows) p0 = *(const float4*)(fbase + (size_t)r0g * d + sc4 * 4);
            if (r1g < rows) p1 = *(const float4*)(fbase + (size_t)r1g * d + sc4 * 4);
            if (t < TR) plab = (nb + t < rows) ? lbls[base + nb + t] : -1;
        }

        // membership ballots over the tile's 256 rows
        int l0 = lbl_t[lane];
        int l1 = lbl_t[lane + 64];
        int l2 = lbl_t[lane + 128];
        int l3 = lbl_t[lane + 192];
        unsigned long long m0 = __ballot(l0 >= 0 && (l0 & 15) == w);
        unsigned long long m1 = __ballot(l1 >= 0 && (l1 & 15) == w);
        unsigned long long m2 = __ballot(l2 >= 0 && (l2 & 15) == w);
        unsigned long long m3 = __ballot(l3 >= 0 && (l3 & 15) == w);

        unsigned long long cur = m0; int mi = 0;
        auto nxt = [&]() -> int {
            for (;;) {
                if (cur) { int b = __ffsll(cur) - 1; cur &= cur - 1; return (mi << 6) + b; }
                if (mi == 3) return -1;
                ++mi;
                cur = (mi == 1) ? m1 : (mi == 2) ? m2 : m3;
            }
        };

        for (;;) {
            int b0 = nxt(); if (b0 < 0) break;
            int b1 = nxt(), b2 = nxt(), b3 = nxt();
            int b4 = nxt(), b5 = nxt(), b6 = nxt(), b7 = nxt();

            int ra = half ? b4 : b0, rb = half ? b5 : b1;
            int rc = half ? b6 : b2, rd = half ? b7 : b3;
            bool va = ra >= 0, vb = rb >= 0, vc = rc >= 0, vd = rd >= 0;
            int la  = va ? lbl_t[ra] : -1;
            int lb  = vb ? lbl_t[rb] : -1;
            int lc  = vc ? lbl_t[rc] : -1;
            int ld_ = vd ? lbl_t[rd] : -1;
            float sa  = va ? stage[ra * W + col] : 0.f;   // 4 independent reads
            float sb  = vb ? stage[rb * W + col] : 0.f;
            float sc_ = vc ? stage[rc * W + col] : 0.f;
            float sd  = vd ? stage[rd * W + col] : 0.f;

            // intra-half dedup (labels are half-uniform scalars)
            if (vb && lb == la) { sa += sb; vb = false; }
            if (vc && lc == la) { sa += sc_; vc = false; }
            else if (vc && vb && lc == lb) { sb += sc_; vc = false; }
            if (vd && ld_ == la) { sa += sd; vd = false; }
            else if (vd && vb && ld_ == lb) { sb += sd; vd = false; }
            else if (vd && vc && ld_ == lc) { sc_ += sd; vd = false; }

            // cross-half dedup: half 0 absorbs, half 1 drops
            int ola  = __shfl_xor(la, 32),  olb  = __shfl_xor(lb, 32);
            int olc  = __shfl_xor(lc, 32),  old_ = __shfl_xor(ld_, 32);
            float osa = __shfl_xor(sa, 32), osb = __shfl_xor(sb, 32);
            float osc = __shfl_xor(sc_, 32), osd = __shfl_xor(sd, 32);
            int met  = (va ? 1 : 0) | (vb ? 2 : 0) | (vc ? 4 : 0) | (vd ? 8 : 0);
            int omet = __shfl_xor(met, 32);
            bool oa = (omet & 1), ob = (omet & 2), oc = (omet & 4), od = (omet & 8);
            if (half == 0) {
                if (oa) { if (va && ola == la) sa += osa; else if (vb && ola == lb) sb += osa; else if (vc && ola == lc) sc_ += osa; else if (vd && ola == ld_) sd += osa; }
                if (ob) { if (va && olb == la) sa += osb; else if (vb && olb == lb) sb += osb; else if (vc && olb == lc) sc_ += osb; else if (vd && olb == ld_) sd += osb; }
                if (oc) { if (va && olc == la) sa += osc; else if (vb && olc == lb) sb += osc; else if (vc && olc == lc) sc_ += osc; else if (vd && olc == ld_) sd += osc; }
                if (od) { if (va && old_ == la) sa += osd; else if (vb && old_ == lb) sb += osd; else if (vc && old_ == lc) sc_ += osd; else if (vd && old_ == ld_) sd += osd; }
            } else {
                if (va && ((oa && ola == la) || (ob && olb == la) || (oc && olc == la) || (od && old_ == la))) va = false;
                if (vb && ((oa && ola == lb) || (ob && olb == lb) || (oc && olc == lb) || (od && old_ == lb))) vb = false;
                if (vc && ((oa && ola == lc) || (ob && olb == lc) || (oc && olc == lc) || (od && old_ == lc))) vc = false;
                if (vd && ((oa && ola == ld_) || (ob && olb == ld_) || (oc && olc == ld_) || (od && old_ == ld_))) vd = false;
            }

            // parallel RMW — addresses now pairwise distinct across the wave
            float xa = 0.f, xb = 0.f, xc = 0.f, xd = 0.f;
            if (va) xa = acc[la * W + col];
            if (vb) xb = acc[lb * W + col];
            if (vc) xc = acc[lc * W + col];
            if (vd) xd = acc[ld_ * W + col];
            if (va) acc[la * W + col] = xa + sa;
            if (vb) acc[lb * W + col] = xb + sb;
            if (vc) acc[lc * W + col] = xc + sc_;
            if (vd) acc[ld_ * W + col] = xd + sd;
        }

        __syncthreads();                 // all waves done reading stage
        if (tile + 1 < ntiles) {
            if (t < TR) lbl_t[t] = plab;
            *(float4*)&stage[sr0 * W + sc4 * 4] = p0;
            *(float4*)&stage[sr1 * W + sc4 * 4] = p1;
        }
        __syncthreads();                 // next tile staged
    }

    // flush: partials[chunk][cls*d + slice*W + col] — coalesced 128 B per class
    float* pbase = partials + (size_t)chunk * c_total * d + slice * W;
    for (int i = t; i < cW; i += SBLK) {
        int cls = i >> 5;
        int cc  = i & (W - 1);
        pbase[(size_t)cls * d + cc] = acc[i];
    }
}

// one block per class: sum chunk partials, Mahalanobis, global scalar reduce;
// last block to finish computes the final scalar (device-scope atomic read).
__global__ __launch_bounds__(256)
void finalize_kernel(const float* __restrict__ partials,
                     const int* __restrict__ counts,
                     const float* __restrict__ proto,
                     const float* __restrict__ cov,
                     float* __restrict__ loss_acc,
                     float* __restrict__ npres_acc,
                     int* __restrict__ done,
                     float* __restrict__ out, int c_total, int d, int nchunks) {
    int c = blockIdx.x;
    int t = threadIdx.x;
    size_t idx = (size_t)c * d + t;
    size_t cstride = (size_t)c_total * d;

    float a = 0.0f;
    for (int k = 0; k < nchunks; ++k)
        a += partials[(size_t)k * cstride + idx];

    int cnt = counts[c];
    float present = (cnt > 0) ? 1.0f : 0.0f;
    float mean = a / fmaxf((float)cnt, 1.0f);
    float diff = mean - proto[idx];
    float pe = present * diff * diff / (cov[idx] + EPS);

    for (int off = 32; off > 0; off >>= 1)
        pe += __shfl_down(pe, off, 64);
    __shared__ float s[4];
    if ((t & 63) == 0) s[t >> 6] = pe;
    __syncthreads();
    if (t == 0) {
        atomicAdd(loss_acc, (s[0] + s[1]) + (s[2] + s[3]));
        atomicAdd(npres_acc, present);
        __threadfence();
        int prev = atomicAdd(done, 1);
        if (prev == c_total - 1) {
            float L = atomicAdd(loss_acc, 0.0f);   // coherent read
            float P = atomicAdd(npres_acc, 0.0f);
            out[0] = L / (P * (float)d);
        }
    }
}

extern "C" void kernel_launch(void* const* d_in, const int* in_sizes, int n_in,
                              void* d_out, int out_size, void* d_ws, size_t ws_size,
                              hipStream_t stream) {
    const float* feats = (const float*)d_in[0];
    const int*   lbls  = (const int*)d_in[1];
    const float* proto = (const float*)d_in[2];
    const float* cov   = (const float*)d_in[3];

    int n_rows = in_sizes[1];              // N = 131072
    int d      = in_sizes[0] / n_rows;     // D = 256
    int c      = in_sizes[2] / d;          // C = 1000

    int*   counts    = (int*)d_ws;
    float* loss_acc  = (float*)d_ws + c;
    float* npres_acc = loss_acc + 1;
    int*   done      = (int*)d_ws + c + 2;
    float* partials  = (float*)d_ws + c + 3;

    hipMemsetAsync(d_ws, 0, ((size_t)c + 3) * sizeof(int), stream);

    int nslices = d / W;                               // 8
    int nchunks = (n_rows + RPC - 1) / RPC;            // 32
    stream_kernel<<<nslices * nchunks, SBLK, 0, stream>>>(
        feats, lbls, partials, counts, n_rows, d, nslices, c);
    finalize_kernel<<<c, 256, 0, stream>>>(partials, counts, proto, cov,
                                           loss_acc, npres_acc, done,
                                           (float*)d_out, c, d, nchunks);
}